// Round 4
// baseline (96.675 us; speedup 1.0000x reference)
//
#include <hip/hip_runtime.h>
#include <math.h>

#define NF 256      // in_features
#define NT 256      // num_trees
#define ND 6        // depth
#define NB 2048     // batch
#define NCOL (NT * ND)   // 1536
#define NLEAF 64         // 2^depth

typedef __attribute__((ext_vector_type(8))) short bf16x8;         // MFMA A/B frag
typedef __attribute__((ext_vector_type(4))) float f32x4;          // MFMA C/D frag
typedef __attribute__((ext_vector_type(8))) unsigned short u16x8; // 16B chunk

__device__ inline unsigned short f2bf(float f) {   // round-to-nearest-even bf16
    unsigned u = __float_as_uint(f);
    u += 0x7fffu + ((u >> 16) & 1u);
    return (unsigned short)(u >> 16);
}
__device__ inline float bf2f(unsigned short h) {
    return __uint_as_float(((unsigned)h) << 16);
}

// ---------------------------------------------------------------------------
// Kernel 1 (512 blocks):
//   blocks 0..383  : Michelot sparsemax, 4 columns/block (1 col/wave),
//                    output TRANSPOSED [col][feature] bf16 hi/lo.
//   blocks 384..511: split x[NB,NF] fp32 -> bf16 hi/lo (coalesced float4).
// ---------------------------------------------------------------------------
__global__ __launch_bounds__(256) void prep_kernel(
    const float* __restrict__ fsl,       // [NF, NCOL]
    const float* __restrict__ x,         // [NB, NF]
    unsigned short* __restrict__ fs_hi,  // [NCOL, NF]
    unsigned short* __restrict__ fs_lo,  // [NCOL, NF]
    unsigned short* __restrict__ xh,     // [NB, NF]
    unsigned short* __restrict__ xl)     // [NB, NF]
{
    const int tid = threadIdx.x;

    if (blockIdx.x >= 384) {
        // ---- x conversion: 128 blocks * 256 threads * 4 float4 = whole x ----
        const int base = (blockIdx.x - 384) * 256 + tid;
        #pragma unroll
        for (int p = 0; p < 4; p++) {
            const int i = (base + p * 32768) * 4;
            const float4 v = *(const float4*)&x[i];
            const unsigned short h0 = f2bf(v.x), h1 = f2bf(v.y),
                                 h2 = f2bf(v.z), h3 = f2bf(v.w);
            *(ushort4*)&xh[i] = make_ushort4(h0, h1, h2, h3);
            *(ushort4*)&xl[i] = make_ushort4(
                f2bf(v.x - bf2f(h0)), f2bf(v.y - bf2f(h1)),
                f2bf(v.z - bf2f(h2)), f2bf(v.w - bf2f(h3)));
        }
        return;
    }

    // ---- sparsemax via Michelot fixed-point, one wave per column ----
    const int lane = tid & 63;
    const int col  = blockIdx.x * 4 + (tid >> 6);

    float xv[4];
    #pragma unroll
    for (int j = 0; j < 4; j++)
        xv[j] = fsl[(lane + 64 * j) * NCOL + col];

    float mx = fmaxf(fmaxf(xv[0], xv[1]), fmaxf(xv[2], xv[3]));
    #pragma unroll
    for (int off = 32; off > 0; off >>= 1)
        mx = fmaxf(mx, __shfl_xor(mx, off));
    #pragma unroll
    for (int j = 0; j < 4; j++) xv[j] -= mx;

    float s = (xv[0] + xv[1]) + (xv[2] + xv[3]);
    #pragma unroll
    for (int off = 32; off > 0; off >>= 1)
        s += __shfl_xor(s, off);
    float tau = (s - 1.0f) / 256.0f;

    int prev = 256;
    for (int it = 0; it < 64; it++) {
        float ss = 0.0f, cc = 0.0f;
        #pragma unroll
        for (int j = 0; j < 4; j++)
            if (xv[j] > tau) { ss += xv[j]; cc += 1.0f; }
        #pragma unroll
        for (int off = 32; off > 0; off >>= 1) {
            ss += __shfl_xor(ss, off);
            cc += __shfl_xor(cc, off);
        }
        const int c = (int)cc;
        if (c == prev) break;
        prev = c;
        tau = (ss - 1.0f) / cc;
    }

    #pragma unroll
    for (int j = 0; j < 4; j++) {
        const float v = fmaxf(xv[j] - tau, 0.0f);
        const unsigned short h = f2bf(v);
        fs_hi[col * NF + lane + 64 * j] = h;
        fs_lo[col * NF + lane + 64 * j] = f2bf(v - bf2f(h));
    }
}

// ---------------------------------------------------------------------------
// Kernel 2: fused split-bf16 MFMA GEMM + tree evaluation.
// 64(M) x 96(N) tile; 96 cols = 16 complete trees. fv stays in LDS.
// acc = Ah*Bh + Ah*Bl + Al*Bh (lo*lo dropped).
// ---------------------------------------------------------------------------
#define TM 64
#define TN 96
#define TK 32
#define PK (TK + 8)   // padded LDS pitch (u16), conflict-free frag reads

union SMem {
    struct {
        unsigned short Ah[TM][PK], Al[TM][PK];
        unsigned short Bh[TN][PK], Bl[TN][PK];
    } st;                                   // 25.6 KB (K-loop)
    struct {
        float fv[TM][TN + 1];               // 64 x 97
        float resp[16][NLEAF];              // 4 KB
        float res[TM][17];                  // transposed output staging
    } ep;                                   // 33.3 KB (epilogue)
};

__global__ __launch_bounds__(256) void gemm_tree_kernel(
    const unsigned short* __restrict__ Ahg,  // xh [NB, NF]
    const unsigned short* __restrict__ Alg,  // xl [NB, NF]
    const unsigned short* __restrict__ Bhg,  // fs hi [NCOL, NF]
    const unsigned short* __restrict__ Blg,  // fs lo [NCOL, NF]
    const float* __restrict__ thr,           // [NT, ND]
    const float* __restrict__ ltemp,         // [NT, ND]
    const float* __restrict__ resp_g,        // [NT, 1, NLEAF]
    float* __restrict__ out)                 // [NB, NT]
{
    __shared__ SMem sm;

    const int tid  = threadIdx.x;
    const int lane = tid & 63;
    const int w    = tid >> 6;
    const int wm   = w & 1;          // wave M pos -> 32 rows
    const int wn   = w >> 1;         // wave N pos -> 48 cols
    const int bm0  = blockIdx.y * TM;
    const int bn0  = blockIdx.x * TN;
    const int t0   = blockIdx.x * 16;

    const int l15  = lane & 15;
    const int quad = lane >> 4;

    // A staging: (row 0..63, kseg 0/8/16/24); B: 128 thr hi, 128 thr lo
    const int arow  = tid >> 2;
    const int akseg = (tid & 3) * 8;
    const int bhalf = tid >> 7;
    const int brow  = (tid & 127) >> 2;
    const int bkseg = (tid & 3) * 8;

    f32x4 acc[2][3] = {};

    for (int k0 = 0; k0 < NF; k0 += TK) {
        *(u16x8*)&sm.st.Ah[arow][akseg] = *(const u16x8*)&Ahg[(bm0 + arow) * NF + k0 + akseg];
        *(u16x8*)&sm.st.Al[arow][akseg] = *(const u16x8*)&Alg[(bm0 + arow) * NF + k0 + akseg];
        {
            const unsigned short* __restrict__ src = bhalf ? Blg : Bhg;
            unsigned short (*dst)[PK] = bhalf ? sm.st.Bl : sm.st.Bh;
            #pragma unroll
            for (int c = 0; c < 3; c++) {
                const int row = c * 32 + brow;
                *(u16x8*)&dst[row][bkseg] =
                    *(const u16x8*)&src[(bn0 + row) * NF + k0 + bkseg];
            }
        }
        __syncthreads();

        // hoist B fragments (reused by both im iterations)
        bf16x8 b_h[3], b_l[3];
        #pragma unroll
        for (int in = 0; in < 3; in++) {
            b_h[in] = *(const bf16x8*)&sm.st.Bh[wn * 48 + in * 16 + l15][quad * 8];
            b_l[in] = *(const bf16x8*)&sm.st.Bl[wn * 48 + in * 16 + l15][quad * 8];
        }
        #pragma unroll
        for (int im = 0; im < 2; im++) {
            const bf16x8 a_h = *(const bf16x8*)&sm.st.Ah[wm * 32 + im * 16 + l15][quad * 8];
            const bf16x8 a_l = *(const bf16x8*)&sm.st.Al[wm * 32 + im * 16 + l15][quad * 8];
            #pragma unroll
            for (int in = 0; in < 3; in++) {
                acc[im][in] = __builtin_amdgcn_mfma_f32_16x16x32_bf16(a_h, b_h[in], acc[im][in], 0, 0, 0);
                acc[im][in] = __builtin_amdgcn_mfma_f32_16x16x32_bf16(a_h, b_l[in], acc[im][in], 0, 0, 0);
                acc[im][in] = __builtin_amdgcn_mfma_f32_16x16x32_bf16(a_l, b_h[in], acc[im][in], 0, 0, 0);
            }
        }
        __syncthreads();
    }

    // ---- epilogue: fv -> LDS (C/D map: row=quad*4+r, col=l15) ----
    #pragma unroll
    for (int im = 0; im < 2; im++)
        #pragma unroll
        for (int in = 0; in < 3; in++)
            #pragma unroll
            for (int r = 0; r < 4; r++)
                sm.ep.fv[wm * 32 + im * 16 + quad * 4 + r][wn * 48 + in * 16 + l15]
                    = acc[im][in][r];
    {
        const int tr  = tid >> 4;
        const int seg = (tid & 15) * 4;
        *(float4*)&sm.ep.resp[tr][seg] = *(const float4*)&resp_g[(t0 + tr) * NLEAF + seg];
    }
    __syncthreads();

    // ---- tree evaluation: 64 rows x 16 trees, 4 items/thread ----
    #pragma unroll
    for (int i = 0; i < 4; i++) {
        const int m   = tid & 63;
        const int t16 = (tid >> 6) + 4 * i;
        const int t   = t0 + t16;

        float sp[ND], sn[ND];
        #pragma unroll
        for (int d = 0; d < ND; d++) {
            const float f  = sm.ep.fv[m][t16 * ND + d];
            const float tl = (f - thr[t * ND + d]) * __expf(-ltemp[t * ND + d]);
            const float h  = 0.5f * tl;
            sp[d] = fminf(fmaxf(0.5f + h, 0.0f), 1.0f);
            sn[d] = fminf(fmaxf(0.5f - h, 0.0f), 1.0f);
        }

        float wleaf[NLEAF];
        wleaf[0] = 1.0f;
        #pragma unroll
        for (int d = 0; d < ND; d++) {
            const int half = 1 << d;
            #pragma unroll
            for (int c = 0; c < NLEAF / 2; c++) {
                if (c < half) {
                    const float base = wleaf[c];
                    wleaf[c + half] = base * sn[d];
                    wleaf[c]        = base * sp[d];
                }
            }
        }

        float a = 0.0f;
        #pragma unroll
        for (int c = 0; c < NLEAF; c++)
            a = fmaf(wleaf[c], sm.ep.resp[t16][c], a);

        sm.ep.res[m][t16] = a;   // pitch 17 -> conflict-free
    }
    __syncthreads();

    // coalesced store: 4 lanes cover one row's 16 trees (64 B)
    {
        const int row = tid >> 2;
        const int j   = (tid & 3) * 4;
        const float4 o = make_float4(sm.ep.res[row][j + 0], sm.ep.res[row][j + 1],
                                     sm.ep.res[row][j + 2], sm.ep.res[row][j + 3]);
        *(float4*)&out[(bm0 + row) * NT + t0 + j] = o;
    }
}

// ---------------------------------------------------------------------------
extern "C" void kernel_launch(void* const* d_in, const int* in_sizes, int n_in,
                              void* d_out, int out_size, void* d_ws, size_t ws_size,
                              hipStream_t stream)
{
    const float* x    = (const float*)d_in[0];  // [2048, 256]
    const float* resp = (const float*)d_in[1];  // [256, 1, 64]
    const float* fsl  = (const float*)d_in[2];  // [256, 256*6]
    const float* thr  = (const float*)d_in[3];  // [256, 6]
    const float* lt   = (const float*)d_in[4];  // [256, 6]
    float* out = (float*)d_out;                 // [2048, 256]

    unsigned short* fs_hi = (unsigned short*)d_ws;          // [NCOL, NF]
    unsigned short* fs_lo = fs_hi + (size_t)NCOL * NF;
    unsigned short* xh    = fs_lo + (size_t)NCOL * NF;      // [NB, NF]
    unsigned short* xl    = xh + (size_t)NB * NF;

    prep_kernel<<<512, 256, 0, stream>>>(fsl, x, fs_hi, fs_lo, xh, xl);

    dim3 g(NCOL / TN, NB / TM);   // (16, 32)
    gemm_tree_kernel<<<g, 256, 0, stream>>>(xh, xl, fs_hi, fs_lo, thr, lt, resp, out);
}

// Round 5
// 90.554 us; speedup vs baseline: 1.0676x; 1.0676x over previous
//
#include <hip/hip_runtime.h>
#include <math.h>

#define NF 256      // in_features
#define NT 256      // num_trees
#define ND 6        // depth
#define NB 2048     // batch
#define NCOL (NT * ND)   // 1536
#define NLEAF 64         // 2^depth

typedef __attribute__((ext_vector_type(8))) short bf16x8;         // MFMA A/B frag
typedef __attribute__((ext_vector_type(4))) float f32x4;          // MFMA C/D frag
typedef __attribute__((ext_vector_type(8))) unsigned short u16x8; // 16B chunk

__device__ inline unsigned short f2bf(float f) {   // round-to-nearest-even bf16
    unsigned u = __float_as_uint(f);
    u += 0x7fffu + ((u >> 16) & 1u);
    return (unsigned short)(u >> 16);
}
__device__ inline float bf2f(unsigned short h) {
    return __uint_as_float(((unsigned)h) << 16);
}

// ---------------------------------------------------------------------------
// Kernel 1: sparsemax per (tree,depth) column via Michelot fixed-point.
// One wave per column, 4 elements/lane, shuffle reductions only (no LDS).
// Output TRANSPOSED [col][feature] bf16 hi/lo.
// ---------------------------------------------------------------------------
__global__ __launch_bounds__(256) void sparsemax_michelot(
    const float* __restrict__ fsl,       // [NF, NCOL]
    unsigned short* __restrict__ fs_hi,  // [NCOL, NF]
    unsigned short* __restrict__ fs_lo)  // [NCOL, NF]
{
    const int lane = threadIdx.x & 63;
    const int col  = blockIdx.x * 4 + (threadIdx.x >> 6);

    float x[4];
    #pragma unroll
    for (int j = 0; j < 4; j++)
        x[j] = fsl[(lane + 64 * j) * NCOL + col];

    float mx = fmaxf(fmaxf(x[0], x[1]), fmaxf(x[2], x[3]));
    #pragma unroll
    for (int off = 32; off > 0; off >>= 1)
        mx = fmaxf(mx, __shfl_xor(mx, off));
    #pragma unroll
    for (int j = 0; j < 4; j++) x[j] -= mx;

    float s = (x[0] + x[1]) + (x[2] + x[3]);
    #pragma unroll
    for (int off = 32; off > 0; off >>= 1)
        s += __shfl_xor(s, off);
    float tau = (s - 1.0f) / 256.0f;

    int prev = 256;
    for (int it = 0; it < 64; it++) {
        float ss = 0.0f, cc = 0.0f;
        #pragma unroll
        for (int j = 0; j < 4; j++)
            if (x[j] > tau) { ss += x[j]; cc += 1.0f; }
        #pragma unroll
        for (int off = 32; off > 0; off >>= 1) {
            ss += __shfl_xor(ss, off);
            cc += __shfl_xor(cc, off);
        }
        const int c = (int)cc;
        if (c == prev) break;
        prev = c;
        tau = (ss - 1.0f) / cc;
    }

    #pragma unroll
    for (int j = 0; j < 4; j++) {
        const float v = fmaxf(x[j] - tau, 0.0f);
        const unsigned short h = f2bf(v);
        fs_hi[col * NF + lane + 64 * j] = h;
        fs_lo[col * NF + lane + 64 * j] = f2bf(v - bf2f(h));
    }
}

// ---------------------------------------------------------------------------
// Kernel 2: fused split-bf16 MFMA GEMM + tree evaluation.
// 64(M) x 96(N) tile; 96 cols = 16 complete trees -> fv stays in LDS.
// A staged from fp32 x with in-register hi/lo split (no extra global pass).
// acc = Ah*Bh + Ah*Bl + Al*Bh (lo*lo dropped; rel err ~2^-18).
// ---------------------------------------------------------------------------
#define TM 64
#define TN 96
#define TK 32
#define PK (TK + 8)   // padded LDS pitch (u16), conflict-free frag reads

union SMem {
    struct {
        unsigned short Ah[TM][PK], Al[TM][PK];
        unsigned short Bh[TN][PK], Bl[TN][PK];
    } st;                                   // ~25.6 KB (K-loop)
    struct {
        float fv[TM][TN + 1];               // 64 x 97
        float resp[16][NLEAF];              // 4 KB
        float res[TM][17];                  // transposed output staging (4.25 KB)
    } ep;                                   // ~33 KB (epilogue)
};

__global__ __launch_bounds__(256) void gemm_tree_kernel(
    const float* __restrict__ x,             // [NB, NF] fp32
    const unsigned short* __restrict__ Bhg,  // fs hi [NCOL, NF]
    const unsigned short* __restrict__ Blg,  // fs lo [NCOL, NF]
    const float* __restrict__ thr,           // [NT, ND]
    const float* __restrict__ ltemp,         // [NT, ND]
    const float* __restrict__ resp_g,        // [NT, 1, NLEAF]
    float* __restrict__ out)                 // [NB, NT]
{
    __shared__ SMem sm;

    const int tid  = threadIdx.x;
    const int lane = tid & 63;
    const int w    = tid >> 6;
    const int wm   = w & 1;          // wave M pos -> 32 rows
    const int wn   = w >> 1;         // wave N pos -> 48 cols
    const int bm0  = blockIdx.y * TM;
    const int bn0  = blockIdx.x * TN;
    const int t0   = blockIdx.x * 16;

    const int l15  = lane & 15;
    const int quad = lane >> 4;

    // A staging: (row 0..63, kseg 0/8/16/24); B: 128 thr hi, 128 thr lo
    const int arow  = tid >> 2;
    const int akseg = (tid & 3) * 8;
    const int bhalf = tid >> 7;
    const int brow  = (tid & 127) >> 2;
    const int bkseg = (tid & 3) * 8;

    f32x4 acc[2][3] = {};

    for (int k0 = 0; k0 < NF; k0 += TK) {
        // ---- A: load fp32, split to bf16 hi/lo in-register ----
        {
            const float4 v0 = *(const float4*)&x[(bm0 + arow) * NF + k0 + akseg];
            const float4 v1 = *(const float4*)&x[(bm0 + arow) * NF + k0 + akseg + 4];
            const float vv[8] = {v0.x, v0.y, v0.z, v0.w, v1.x, v1.y, v1.z, v1.w};
            u16x8 hi, lo;
            #pragma unroll
            for (int j = 0; j < 8; j++) {
                const unsigned short h = f2bf(vv[j]);
                hi[j] = h;
                lo[j] = f2bf(vv[j] - bf2f(h));
            }
            *(u16x8*)&sm.st.Ah[arow][akseg] = hi;
            *(u16x8*)&sm.st.Al[arow][akseg] = lo;
        }
        // ---- B: copy bf16 hi/lo tiles (96 rows x 32 k each) ----
        {
            const unsigned short* __restrict__ src = bhalf ? Blg : Bhg;
            unsigned short (*dst)[PK] = bhalf ? sm.st.Bl : sm.st.Bh;
            #pragma unroll
            for (int c = 0; c < 3; c++) {
                const int row = c * 32 + brow;
                *(u16x8*)&dst[row][bkseg] =
                    *(const u16x8*)&src[(bn0 + row) * NF + k0 + bkseg];
            }
        }
        __syncthreads();

        #pragma unroll
        for (int im = 0; im < 2; im++) {
            const bf16x8 a_h = *(const bf16x8*)&sm.st.Ah[wm * 32 + im * 16 + l15][quad * 8];
            const bf16x8 a_l = *(const bf16x8*)&sm.st.Al[wm * 32 + im * 16 + l15][quad * 8];
            #pragma unroll
            for (int in = 0; in < 3; in++) {
                const bf16x8 b_h = *(const bf16x8*)&sm.st.Bh[wn * 48 + in * 16 + l15][quad * 8];
                const bf16x8 b_l = *(const bf16x8*)&sm.st.Bl[wn * 48 + in * 16 + l15][quad * 8];
                acc[im][in] = __builtin_amdgcn_mfma_f32_16x16x32_bf16(a_h, b_h, acc[im][in], 0, 0, 0);
                acc[im][in] = __builtin_amdgcn_mfma_f32_16x16x32_bf16(a_h, b_l, acc[im][in], 0, 0, 0);
                acc[im][in] = __builtin_amdgcn_mfma_f32_16x16x32_bf16(a_l, b_h, acc[im][in], 0, 0, 0);
            }
        }
        __syncthreads();
    }

    // ---- epilogue: fv -> LDS (C/D map: row=quad*4+r, col=l15) ----
    #pragma unroll
    for (int im = 0; im < 2; im++)
        #pragma unroll
        for (int in = 0; in < 3; in++)
            #pragma unroll
            for (int r = 0; r < 4; r++)
                sm.ep.fv[wm * 32 + im * 16 + quad * 4 + r][wn * 48 + in * 16 + l15]
                    = acc[im][in][r];
    {
        const int tr  = tid >> 4;
        const int seg = (tid & 15) * 4;
        *(float4*)&sm.ep.resp[tr][seg] = *(const float4*)&resp_g[(t0 + tr) * NLEAF + seg];
    }
    __syncthreads();

    // ---- tree evaluation: 64 rows x 16 trees, 4 items/thread ----
    #pragma unroll
    for (int i = 0; i < 4; i++) {
        const int m   = tid & 63;
        const int t16 = (tid >> 6) + 4 * i;
        const int t   = t0 + t16;

        float sp[ND], sn[ND];
        #pragma unroll
        for (int d = 0; d < ND; d++) {
            const float f  = sm.ep.fv[m][t16 * ND + d];
            const float tl = (f - thr[t * ND + d]) * __expf(-ltemp[t * ND + d]);
            const float h  = 0.5f * tl;
            sp[d] = fminf(fmaxf(0.5f + h, 0.0f), 1.0f);
            sn[d] = fminf(fmaxf(0.5f - h, 0.0f), 1.0f);
        }

        float wleaf[NLEAF];
        wleaf[0] = 1.0f;
        #pragma unroll
        for (int d = 0; d < ND; d++) {
            const int half = 1 << d;
            #pragma unroll
            for (int c = 0; c < NLEAF / 2; c++) {
                if (c < half) {
                    const float base = wleaf[c];
                    wleaf[c + half] = base * sn[d];
                    wleaf[c]        = base * sp[d];
                }
            }
        }

        float a = 0.0f;
        #pragma unroll
        for (int c = 0; c < NLEAF; c++)
            a = fmaf(wleaf[c], sm.ep.resp[t16][c], a);

        sm.ep.res[m][t16] = a;   // pitch 17 -> conflict-free
    }
    __syncthreads();

    // coalesced store: 4 lanes cover one row's 16 trees (16 B/lane)
    {
        const int row = tid >> 2;
        const int j   = (tid & 3) * 4;
        const float4 o = make_float4(sm.ep.res[row][j + 0], sm.ep.res[row][j + 1],
                                     sm.ep.res[row][j + 2], sm.ep.res[row][j + 3]);
        *(float4*)&out[(bm0 + row) * NT + t0 + j] = o;
    }
}

// ---------------------------------------------------------------------------
extern "C" void kernel_launch(void* const* d_in, const int* in_sizes, int n_in,
                              void* d_out, int out_size, void* d_ws, size_t ws_size,
                              hipStream_t stream)
{
    const float* x    = (const float*)d_in[0];  // [2048, 256]
    const float* resp = (const float*)d_in[1];  // [256, 1, 64]
    const float* fsl  = (const float*)d_in[2];  // [256, 256*6]
    const float* thr  = (const float*)d_in[3];  // [256, 6]
    const float* lt   = (const float*)d_in[4];  // [256, 6]
    float* out = (float*)d_out;                 // [2048, 256]

    unsigned short* fs_hi = (unsigned short*)d_ws;          // [NCOL, NF]
    unsigned short* fs_lo = fs_hi + (size_t)NCOL * NF;

    sparsemax_michelot<<<NCOL / 4, 256, 0, stream>>>(fsl, fs_hi, fs_lo);

    dim3 g(NCOL / TN, NB / TM);   // (16, 32)
    gemm_tree_kernel<<<g, 256, 0, stream>>>(x, fs_hi, fs_lo, thr, lt, resp, out);
}